// Round 5
// baseline (1564.308 us; speedup 1.0000x reference)
//
#include <hip/hip_runtime.h>
#include <hip/hip_bf16.h>
#include <math.h>

#define NN 4096
#define NE 1024
#define DIN 256
#define HD 64

typedef __hip_bfloat16 bf16;
__device__ __forceinline__ float b2f(bf16 x){ return __bfloat162float(x); }

// ---- 1. adj column sums (atomic partials over row chunks) ----
__global__ void k_colsum(const float* __restrict__ adj, float* __restrict__ colsum){
  int e  = blockIdx.x*256 + threadIdx.x;
  int i0 = blockIdx.y*128;
  float acc = 0.f;
  for (int i = 0; i < 128; ++i)
    acc += adj[(size_t)(i0+i)*NE + e];
  atomicAdd(&colsum[e], acc);
}

// ---- 2. ecT[e][c] = (feats^T @ adj)[c][e] / colsum[e]  M=c(256) N=e(1024) K=i(4096)
__global__ void k_ect(const float* __restrict__ feats, const float* __restrict__ adj,
                      const float* __restrict__ colsum, float* __restrict__ ecT){
  __shared__ float As[64][65]; // [k(i)][m(c)]
  __shared__ float Bs[64][65]; // [k(i)][n(e)]
  int c0 = blockIdx.x*64, e0 = blockIdx.y*64;
  int tid = threadIdx.x, tx = tid & 15, ty = tid >> 4;
  float acc[4][4] = {};
  for (int k0 = 0; k0 < NN; k0 += 64){
    for (int idx = tid; idx < 4096; idx += 256){
      int r = idx >> 6, c = idx & 63;
      As[r][c] = feats[(size_t)(k0+r)*DIN + c0 + c];
      Bs[r][c] = adj  [(size_t)(k0+r)*NE  + e0 + c];
    }
    __syncthreads();
    for (int k = 0; k < 64; ++k){
      float a[4], b[4];
      #pragma unroll
      for (int i=0;i<4;++i) a[i] = As[k][tx*4+i];
      #pragma unroll
      for (int i=0;i<4;++i) b[i] = Bs[k][ty*4+i];
      #pragma unroll
      for (int mi=0;mi<4;++mi)
        #pragma unroll
        for (int ni=0;ni<4;++ni) acc[mi][ni] += a[mi]*b[ni];
    }
    __syncthreads();
  }
  for (int mi=0;mi<4;++mi)
    for (int ni=0;ni<4;++ni){
      int cc = c0 + tx*4 + mi, ee = e0 + ty*4 + ni;
      ecT[(size_t)ee*DIN + cc] = acc[mi][ni] / colsum[ee];
    }
}

// ---- 3. s = LN1(ecT @ lin_w^T); sw = s*w_o, sq_s = sum_h w*s^2 ----
__global__ void k_s(const float* __restrict__ ecT, const float* __restrict__ lin_w,
                    const float* __restrict__ ln1w, const float* __restrict__ ln1b,
                    const float* __restrict__ wow,
                    float* __restrict__ sw, float* __restrict__ sq_s){
  int e = blockIdx.x, h = threadIdx.x;
  const float* row = ecT + (size_t)e*DIN;
  const float* lw  = lin_w + (size_t)h*DIN;
  float acc = 0.f;
  for (int c = 0; c < DIN; ++c) acc += row[c]*lw[c];
  float tot = acc;
  for (int m=32;m>=1;m>>=1) tot += __shfl_xor(tot,m);
  float mean = tot*(1.f/64.f);
  float dv = acc - mean;
  float vv = dv*dv;
  for (int m=32;m>=1;m>>=1) vv += __shfl_xor(vv,m);
  float y = dv*(1.f/sqrtf(vv*(1.f/64.f)+1e-5f))*ln1w[h] + ln1b[h];
  float wv = wow[h];
  sw[(size_t)e*HD + h] = y*wv;
  float q = wv*y*y;
  for (int m=32;m>=1;m>>=1) q += __shfl_xor(q,m);
  if (h==0) sq_s[e] = q;
}

// ---- 4. f = feats @ W_v^T   M=i(4096) N=h(64) K=c(256) ----
__global__ void k_f(const float* __restrict__ feats, const float* __restrict__ Wv,
                    float* __restrict__ f){
  __shared__ float As[64][65]; // [k(c)][m(i)]
  __shared__ float Bs[64][65]; // [k(c)][n(h)]
  int i0 = blockIdx.x*64;
  int tid=threadIdx.x, tx=tid&15, ty=tid>>4;
  float acc[4][4]={};
  for (int c0=0;c0<DIN;c0+=64){
    for (int idx=tid; idx<4096; idx+=256){
      int r=idx>>6, c=idx&63;
      As[c][r] = feats[(size_t)(i0+r)*DIN + c0+c];
      Bs[c][r] = Wv   [(size_t)r*DIN      + c0+c];
    }
    __syncthreads();
    for (int k=0;k<64;++k){
      float a[4], b[4];
      #pragma unroll
      for (int i=0;i<4;++i) a[i] = As[k][tx*4+i];
      #pragma unroll
      for (int i=0;i<4;++i) b[i] = Bs[k][ty*4+i];
      #pragma unroll
      for (int mi=0;mi<4;++mi)
        #pragma unroll
        for (int ni=0;ni<4;++ni) acc[mi][ni] += a[mi]*b[ni];
    }
    __syncthreads();
  }
  for (int mi=0;mi<4;++mi)
    for (int ni=0;ni<4;++ni)
      f[(size_t)(i0+tx*4+mi)*HD + ty*4+ni] = acc[mi][ni];
}

// ---- 5. rowsum[i] = sum_j exp(f_i . f_j / 8)  (|S|<=~13 -> exp finite, no max) ----
__global__ void k_rowsum(const float* __restrict__ f, float* __restrict__ rowsum){
  __shared__ float Fi[64][65];  // [h][i_local]
  __shared__ float Fj[64][65];  // [h][j_local]
  __shared__ float red[64][17];
  int i0 = blockIdx.x*64;
  int tid=threadIdx.x, tx=tid&15, ty=tid>>4;
  for (int idx=tid; idx<4096; idx+=256){
    int r=idx>>6, c=idx&63;
    Fi[c][r] = f[(size_t)(i0+r)*HD + c];
  }
  float psum[4] = {0.f,0.f,0.f,0.f};
  for (int jt=0; jt<8; ++jt){
    int j0 = blockIdx.y*512 + jt*64;
    __syncthreads();
    for (int idx=tid; idx<4096; idx+=256){
      int r=idx>>6, c=idx&63;
      Fj[c][r] = f[(size_t)(j0+r)*HD + c];
    }
    __syncthreads();
    float acc[4][4]={};
    for (int k=0;k<64;++k){
      float a[4], b[4];
      #pragma unroll
      for (int i=0;i<4;++i) a[i] = Fi[k][tx*4+i];
      #pragma unroll
      for (int i=0;i<4;++i) b[i] = Fj[k][ty*4+i];
      #pragma unroll
      for (int mi=0;mi<4;++mi)
        #pragma unroll
        for (int ni=0;ni<4;++ni) acc[mi][ni] += a[mi]*b[ni];
    }
    #pragma unroll
    for (int mi=0;mi<4;++mi)
      #pragma unroll
      for (int ni=0;ni<4;++ni) psum[mi] += __expf(acc[mi][ni]*0.125f);
  }
  __syncthreads();
  for (int mi=0;mi<4;++mi) red[tx*4+mi][ty] = psum[mi];
  __syncthreads();
  if (tid < 64){
    float s = 0.f;
    for (int t=0;t<16;++t) s += red[tid][t];
    atomicAdd(&rowsum[i0+tid], s);
  }
}

// ---- 6. dpre_unnorm += exp(S_tile) @ f_tile  (3 LDS arrays = 49.9 KB; P reuses FjT) ----
__global__ void k_av(const float* __restrict__ f, float* __restrict__ dpre){
  __shared__ float Fi [64][65]; // [h][i]
  __shared__ float FjT[64][65]; // [h][j] for scores; then P[j][i]
  __shared__ float Fj [64][65]; // [j][h] for PV
  int i0 = blockIdx.x*64;
  int tid=threadIdx.x, tx=tid&15, ty=tid>>4;
  for (int idx=tid; idx<4096; idx+=256){
    int r=idx>>6, c=idx&63;
    Fi[c][r] = f[(size_t)(i0+r)*HD + c];
  }
  float acco[4][4]={};  // [mi(i)][hi(h)]
  for (int jt=0; jt<16; ++jt){
    int j0 = blockIdx.y*1024 + jt*64;
    __syncthreads();
    for (int idx=tid; idx<4096; idx+=256){
      int r=idx>>6, c=idx&63;
      float v = f[(size_t)(j0+r)*HD + c];
      FjT[c][r] = v;
      Fj [r][c] = v;
    }
    __syncthreads();
    float accs[4][4]={};   // [mi(i)][ni(j)]
    for (int k=0;k<64;++k){
      float a[4], b[4];
      #pragma unroll
      for (int i=0;i<4;++i) a[i] = Fi [k][tx*4+i];
      #pragma unroll
      for (int i=0;i<4;++i) b[i] = FjT[k][ty*4+i];
      #pragma unroll
      for (int mi=0;mi<4;++mi)
        #pragma unroll
        for (int ni=0;ni<4;++ni) accs[mi][ni] += a[mi]*b[ni];
    }
    __syncthreads();   // everyone done reading FjT as scores operand
    #pragma unroll
    for (int mi=0;mi<4;++mi)
      #pragma unroll
      for (int ni=0;ni<4;++ni)
        FjT[ty*4+ni][tx*4+mi] = __expf(accs[mi][ni]*0.125f);  // P[j][i]
    __syncthreads();
    for (int k=0;k<64;++k){
      float p[4], b[4];
      #pragma unroll
      for (int i=0;i<4;++i) p[i] = FjT[k][tx*4+i];   // P[j=k][i]
      #pragma unroll
      for (int i=0;i<4;++i) b[i] = Fj [k][ty*4+i];   // f[j=k][h]
      #pragma unroll
      for (int mi=0;mi<4;++mi)
        #pragma unroll
        for (int hi=0;hi<4;++hi) acco[mi][hi] += p[mi]*b[hi];
    }
  }
  for (int mi=0;mi<4;++mi)
    for (int hi=0;hi<4;++hi)
      atomicAdd(&dpre[(size_t)(i0+tx*4+mi)*HD + ty*4+hi], acco[mi][hi]);
}

// ---- 7. d = LN2(dpre/rowsum); dmat, sq_d. One wave per row ----
__global__ void k_dln(const float* __restrict__ dpre, const float* __restrict__ rowsum,
                      const float* __restrict__ ln2w, const float* __restrict__ ln2b,
                      const float* __restrict__ wow,
                      float* __restrict__ dmat, float* __restrict__ sq_d){
  int lane = threadIdx.x & 63;
  int n = blockIdx.x*4 + (threadIdx.x>>6);
  float x = dpre[(size_t)n*HD + lane] / rowsum[n];
  float tot = x;
  for (int m=32;m>=1;m>>=1) tot += __shfl_xor(tot,m);
  float mean = tot*(1.f/64.f);
  float dv = x - mean;
  float vv = dv*dv;
  for (int m=32;m>=1;m>>=1) vv += __shfl_xor(vv,m);
  float y = dv*(1.f/sqrtf(vv*(1.f/64.f)+1e-5f))*ln2w[lane] + ln2b[lane];
  dmat[(size_t)n*HD + lane] = y;
  float wv = wow[lane];
  float q = wv*y*y;
  for (int m=32;m>=1;m>>=1) q += __shfl_xor(q,m);
  if (lane==0) sq_d[n] = q;
}

// ---- 8. Hm[n][e] = exp(-(sq_s[e]+sq_d[n]-2*dot(sw[e],d[n])+b)/800), store bf16 ----
__global__ void k_hm(const float* __restrict__ dmat, const float* __restrict__ sw,
                     const float* __restrict__ sq_d, const float* __restrict__ sq_s,
                     const float* __restrict__ wob, bf16* __restrict__ Hm){
  __shared__ float As[64][65]; // [k(h)][m(n)]
  __shared__ float Bs[64][65]; // [k(h)][n(e)]
  int n0 = blockIdx.x*64, e0 = blockIdx.y*64;
  int tid=threadIdx.x, tx=tid&15, ty=tid>>4;
  for (int idx=tid; idx<4096; idx+=256){
    int r=idx>>6, c=idx&63;
    As[c][r] = dmat[(size_t)(n0+r)*HD + c];
    Bs[c][r] = sw  [(size_t)(e0+r)*HD + c];
  }
  __syncthreads();
  float acc[4][4]={};
  for (int k=0;k<64;++k){
    float a[4], b[4];
    #pragma unroll
    for (int i=0;i<4;++i) a[i] = As[k][tx*4+i];
    #pragma unroll
    for (int i=0;i<4;++i) b[i] = Bs[k][ty*4+i];
    #pragma unroll
    for (int mi=0;mi<4;++mi)
      #pragma unroll
      for (int ni=0;ni<4;++ni) acc[mi][ni] += a[mi]*b[ni];
  }
  float bias = wob[0];
  for (int mi=0;mi<4;++mi)
    for (int ni=0;ni<4;++ni){
      int nn = n0+tx*4+mi, ee = e0+ty*4+ni;
      float ta = sq_s[ee] + sq_d[nn] - 2.f*acc[mi][ni] + bias;
      float arg = -ta*(1.f/800.f);
      if (!(arg > -88.f)) arg = -88.f;
      if (arg > 60.f)     arg = 60.f;
      Hm[(size_t)nn*NE + ee] = __float2bfloat16(__expf(arg));
    }
}

// ---- 9. invDV[n] = (row sum of Hm)^-0.5 ----
__global__ void k_dv(const bf16* __restrict__ Hm, float* __restrict__ invDV){
  __shared__ float sm[256];
  int n = blockIdx.x, t = threadIdx.x;
  const bf16* row = Hm + (size_t)n*NE;
  float a = b2f(row[t]) + b2f(row[t+256]) + b2f(row[t+512]) + b2f(row[t+768]);
  sm[t]=a; __syncthreads();
  for (int s=128;s>0;s>>=1){ if(t<s) sm[t]+=sm[t+s]; __syncthreads(); }
  if (t==0){ float v = sm[0]; invDV[n] = (v>0.f) ? 1.f/sqrtf(v) : 0.f; }
}

// ---- 10. DE col sums -> invDE ----
__global__ void k_de(const bf16* __restrict__ Hm, float* __restrict__ DE){
  int e  = blockIdx.x*256 + threadIdx.x;
  int i0 = blockIdx.y*128;
  float acc=0.f;
  for (int i=0;i<128;++i) acc += b2f(Hm[(size_t)(i0+i)*NE + e]);
  atomicAdd(&DE[e], acc);
}
__global__ void k_invde(float* __restrict__ DE){
  int e = blockIdx.x*256 + threadIdx.x;
  float v = DE[e];
  DE[e] = (v>0.f) ? 1.f/v : 0.f;
}

// ---- 11. out = 0.99*G + 0.01*invDV_i*invDV_j*sum_e Hm[i,e]*invDE[e]*Hm[j,e]
//      symmetric: compute upper-tri 64x64 tiles, mirror via LDS ----
__global__ void k_final(const bf16* __restrict__ Hm, const float* __restrict__ invDE,
                        const float* __restrict__ invDV, const float* __restrict__ G,
                        float* __restrict__ out){
  int bi = blockIdx.x, bj = blockIdx.y;
  if (bj < bi) return;
  __shared__ float As[64][65]; // [k(e)][m(i)]
  __shared__ float Bs[64][65]; // [k(e)][n(j)]
  int i0 = bi*64, j0 = bj*64;
  int tid=threadIdx.x, tx=tid&15, ty=tid>>4;
  float acc[4][4]={};
  for (int k0=0;k0<NE;k0+=64){
    for (int idx=tid; idx<4096; idx+=256){
      int r=idx>>6, c=idx&63;
      As[c][r] = b2f(Hm[(size_t)(i0+r)*NE + k0+c])*invDE[k0+c];
      Bs[c][r] = b2f(Hm[(size_t)(j0+r)*NE + k0+c]);
    }
    __syncthreads();
    for (int k=0;k<64;++k){
      float a[4], b[4];
      #pragma unroll
      for (int i=0;i<4;++i) a[i] = As[k][tx*4+i];
      #pragma unroll
      for (int i=0;i<4;++i) b[i] = Bs[k][ty*4+i];
      #pragma unroll
      for (int mi=0;mi<4;++mi)
        #pragma unroll
        for (int ni=0;ni<4;++ni) acc[mi][ni] += a[mi]*b[ni];
    }
    __syncthreads();
  }
  float gnv[4][4];
  for (int mi=0;mi<4;++mi){
    int ii = i0+tx*4+mi;
    float di = invDV[ii];
    for (int ni=0;ni<4;++ni){
      int jj = j0+ty*4+ni;
      float gn = di*invDV[jj]*acc[mi][ni];
      gnv[mi][ni] = gn;
      size_t o = (size_t)ii*NN + jj;
      out[o] = 0.99f*G[o] + 0.01f*gn;
    }
  }
  if (bi==bj) return;  // uniform across block
  __syncthreads();
  for (int mi=0;mi<4;++mi)
    for (int ni=0;ni<4;++ni)
      As[tx*4+mi][ty*4+ni] = gnv[mi][ni];   // As[i_local][j_local]
  __syncthreads();
  for (int idx=tid; idx<4096; idx+=256){
    int r=idx>>6, c=idx&63;  // r=j_local, c=i_local
    size_t o = (size_t)(j0+r)*NN + i0+c;
    out[o] = 0.99f*G[o] + 0.01f*As[c][r];
  }
}

extern "C" void kernel_launch(void* const* d_in, const int* in_sizes, int n_in,
                              void* d_out, int out_size, void* d_ws, size_t ws_size,
                              hipStream_t stream){
  const float* adj  = (const float*)d_in[0];
  const float* G    = (const float*)d_in[1];
  const float* feats= (const float*)d_in[2];
  const float* Wv   = (const float*)d_in[3];
  const float* lin  = (const float*)d_in[4];
  const float* wow  = (const float*)d_in[5];
  const float* wob  = (const float*)d_in[6];
  const float* ln1w = (const float*)d_in[7];
  const float* ln1b = (const float*)d_in[8];
  const float* ln2w = (const float*)d_in[9];
  const float* ln2b = (const float*)d_in[10];
  float* out = (float*)d_out;

  // workspace: ~4.5 MB fp32 + 8 MB bf16 Hm
  float* w = (float*)d_ws;
  float* colsum = w; w += NE;
  float* DE     = w; w += NE;   // becomes invDE in place
  float* sq_s   = w; w += NE;
  float* rowsum = w; w += NN;
  float* sq_d   = w; w += NN;
  float* invDV  = w; w += NN;
  float* ecT    = w; w += NE*DIN;
  float* swp    = w; w += NE*HD;
  float* f      = w; w += NN*HD;
  float* dpre   = w; w += NN*HD;
  float* dmat   = w; w += NN*HD;
  bf16*  Hm     = (bf16*)w;     // NN*NE bf16 = 8 MB

  hipMemsetAsync(colsum, 0, NE*sizeof(float), stream);
  hipMemsetAsync(DE,     0, NE*sizeof(float), stream);
  hipMemsetAsync(rowsum, 0, NN*sizeof(float), stream);
  hipMemsetAsync(dpre,   0, (size_t)NN*HD*sizeof(float), stream);

  k_colsum <<<dim3(4,32), 256, 0, stream>>>(adj, colsum);
  k_ect    <<<dim3(4,16), 256, 0, stream>>>(feats, adj, colsum, ecT);
  k_s      <<<NE,          64, 0, stream>>>(ecT, lin, ln1w, ln1b, wow, swp, sq_s);
  k_f      <<<64,         256, 0, stream>>>(feats, Wv, f);
  k_rowsum <<<dim3(64,8), 256, 0, stream>>>(f, rowsum);
  k_av     <<<dim3(64,4), 256, 0, stream>>>(f, dpre);
  k_dln    <<<NN/4,       256, 0, stream>>>(dpre, rowsum, ln2w, ln2b, wow, dmat, sq_d);
  k_hm     <<<dim3(64,16),256, 0, stream>>>(dmat, swp, sq_d, sq_s, wob, Hm);
  k_dv     <<<NN,         256, 0, stream>>>(Hm, invDV);
  k_de     <<<dim3(4,32), 256, 0, stream>>>(Hm, DE);
  k_invde  <<<4,          256, 0, stream>>>(DE);
  k_final  <<<dim3(64,64),256, 0, stream>>>(Hm, DE, invDV, G, out);
}

// Round 6
// 1049.905 us; speedup vs baseline: 1.4900x; 1.4900x over previous
//
#include <hip/hip_runtime.h>
#include <hip/hip_bf16.h>
#include <math.h>

#define NN 4096
#define NE 1024
#define DIN 256
#define HD 64

typedef __hip_bfloat16 bf16;
__device__ __forceinline__ float b2f(bf16 x){ return __bfloat162float(x); }

// ---- 1. adj column sums (atomic partials over row chunks) ----
__global__ void k_colsum(const float* __restrict__ adj, float* __restrict__ colsum){
  int e  = blockIdx.x*256 + threadIdx.x;
  int i0 = blockIdx.y*128;
  float acc = 0.f;
  for (int i = 0; i < 128; ++i)
    acc += adj[(size_t)(i0+i)*NE + e];
  atomicAdd(&colsum[e], acc);
}

// ---- 2. ecT_raw[e][c] += (feats^T @ adj)[c][e] over K chunk.
//      grid (4,16,16): z = 256-row K chunk. 1024 blocks (was 64 -> 1 wave/CU,
//      latency-starved at 610us). Division by colsum folded into k_s. ----
__global__ void k_ect(const float* __restrict__ feats, const float* __restrict__ adj,
                      float* __restrict__ ecT){
  __shared__ float As[64][65]; // [k(i)][m(c)]
  __shared__ float Bs[64][65]; // [k(i)][n(e)]
  int c0 = blockIdx.x*64, e0 = blockIdx.y*64;
  int kb = blockIdx.z*256;
  int tid = threadIdx.x, tx = tid & 15, ty = tid >> 4;
  float acc[4][4] = {};
  for (int k0 = kb; k0 < kb+256; k0 += 64){
    for (int idx = tid; idx < 4096; idx += 256){
      int r = idx >> 6, c = idx & 63;
      As[r][c] = feats[(size_t)(k0+r)*DIN + c0 + c];
      Bs[r][c] = adj  [(size_t)(k0+r)*NE  + e0 + c];
    }
    __syncthreads();
    for (int k = 0; k < 64; ++k){
      float a[4], b[4];
      #pragma unroll
      for (int i=0;i<4;++i) a[i] = As[k][tx*4+i];
      #pragma unroll
      for (int i=0;i<4;++i) b[i] = Bs[k][ty*4+i];
      #pragma unroll
      for (int mi=0;mi<4;++mi)
        #pragma unroll
        for (int ni=0;ni<4;++ni) acc[mi][ni] += a[mi]*b[ni];
    }
    __syncthreads();
  }
  for (int mi=0;mi<4;++mi)
    for (int ni=0;ni<4;++ni){
      int cc = c0 + tx*4 + mi, ee = e0 + ty*4 + ni;
      atomicAdd(&ecT[(size_t)ee*DIN + cc], acc[mi][ni]);
    }
}

// ---- 3. s = LN1((ecT/colsum) @ lin_w^T); sw = s*w_o, sq_s = sum_h w*s^2 ----
__global__ void k_s(const float* __restrict__ ecT, const float* __restrict__ colsum,
                    const float* __restrict__ lin_w,
                    const float* __restrict__ ln1w, const float* __restrict__ ln1b,
                    const float* __restrict__ wow,
                    float* __restrict__ sw, float* __restrict__ sq_s){
  int e = blockIdx.x, h = threadIdx.x;
  const float* row = ecT + (size_t)e*DIN;
  const float* lw  = lin_w + (size_t)h*DIN;
  float acc = 0.f;
  for (int c = 0; c < DIN; ++c) acc += row[c]*lw[c];
  acc /= colsum[e];                 // exact: dot is linear in the ecT row
  float tot = acc;
  for (int m=32;m>=1;m>>=1) tot += __shfl_xor(tot,m);
  float mean = tot*(1.f/64.f);
  float dv = acc - mean;
  float vv = dv*dv;
  for (int m=32;m>=1;m>>=1) vv += __shfl_xor(vv,m);
  float y = dv*(1.f/sqrtf(vv*(1.f/64.f)+1e-5f))*ln1w[h] + ln1b[h];
  float wv = wow[h];
  sw[(size_t)e*HD + h] = y*wv;
  float q = wv*y*y;
  for (int m=32;m>=1;m>>=1) q += __shfl_xor(q,m);
  if (h==0) sq_s[e] = q;
}

// ---- 4. f += feats @ W_v^T over K chunk. grid (64,4): z = 64-col K chunk ----
__global__ void k_f(const float* __restrict__ feats, const float* __restrict__ Wv,
                    float* __restrict__ f){
  __shared__ float As[64][65]; // [k(c)][m(i)]
  __shared__ float Bs[64][65]; // [k(c)][n(h)]
  int i0 = blockIdx.x*64;
  int c0 = blockIdx.y*64;
  int tid=threadIdx.x, tx=tid&15, ty=tid>>4;
  float acc[4][4]={};
  for (int idx=tid; idx<4096; idx+=256){
    int r=idx>>6, c=idx&63;
    As[c][r] = feats[(size_t)(i0+r)*DIN + c0+c];
    Bs[c][r] = Wv   [(size_t)r*DIN      + c0+c];
  }
  __syncthreads();
  for (int k=0;k<64;++k){
    float a[4], b[4];
    #pragma unroll
    for (int i=0;i<4;++i) a[i] = As[k][tx*4+i];
    #pragma unroll
    for (int i=0;i<4;++i) b[i] = Bs[k][ty*4+i];
    #pragma unroll
    for (int mi=0;mi<4;++mi)
      #pragma unroll
      for (int ni=0;ni<4;++ni) acc[mi][ni] += a[mi]*b[ni];
  }
  for (int mi=0;mi<4;++mi)
    for (int ni=0;ni<4;++ni)
      atomicAdd(&f[(size_t)(i0+tx*4+mi)*HD + ty*4+ni], acc[mi][ni]);
}

// ---- 5. rowsum[i] = sum_j exp(f_i . f_j / 8)  (|S|<=~13 -> exp finite, no max) ----
__global__ void k_rowsum(const float* __restrict__ f, float* __restrict__ rowsum){
  __shared__ float Fi[64][65];  // [h][i_local]
  __shared__ float Fj[64][65];  // [h][j_local]
  __shared__ float red[64][17];
  int i0 = blockIdx.x*64;
  int tid=threadIdx.x, tx=tid&15, ty=tid>>4;
  for (int idx=tid; idx<4096; idx+=256){
    int r=idx>>6, c=idx&63;
    Fi[c][r] = f[(size_t)(i0+r)*HD + c];
  }
  float psum[4] = {0.f,0.f,0.f,0.f};
  for (int jt=0; jt<8; ++jt){
    int j0 = blockIdx.y*512 + jt*64;
    __syncthreads();
    for (int idx=tid; idx<4096; idx+=256){
      int r=idx>>6, c=idx&63;
      Fj[c][r] = f[(size_t)(j0+r)*HD + c];
    }
    __syncthreads();
    float acc[4][4]={};
    for (int k=0;k<64;++k){
      float a[4], b[4];
      #pragma unroll
      for (int i=0;i<4;++i) a[i] = Fi[k][tx*4+i];
      #pragma unroll
      for (int i=0;i<4;++i) b[i] = Fj[k][ty*4+i];
      #pragma unroll
      for (int mi=0;mi<4;++mi)
        #pragma unroll
        for (int ni=0;ni<4;++ni) acc[mi][ni] += a[mi]*b[ni];
    }
    #pragma unroll
    for (int mi=0;mi<4;++mi)
      #pragma unroll
      for (int ni=0;ni<4;++ni) psum[mi] += __expf(acc[mi][ni]*0.125f);
  }
  __syncthreads();
  for (int mi=0;mi<4;++mi) red[tx*4+mi][ty] = psum[mi];
  __syncthreads();
  if (tid < 64){
    float s = 0.f;
    for (int t=0;t<16;++t) s += red[tid][t];
    atomicAdd(&rowsum[i0+tid], s);
  }
}

// ---- 6. dpre_unnorm += exp(S_tile) @ f_tile  (P reuses FjT; 49.9 KB LDS) ----
__global__ void k_av(const float* __restrict__ f, float* __restrict__ dpre){
  __shared__ float Fi [64][65]; // [h][i]
  __shared__ float FjT[64][65]; // [h][j] for scores; then P[j][i]
  __shared__ float Fj [64][65]; // [j][h] for PV
  int i0 = blockIdx.x*64;
  int tid=threadIdx.x, tx=tid&15, ty=tid>>4;
  for (int idx=tid; idx<4096; idx+=256){
    int r=idx>>6, c=idx&63;
    Fi[c][r] = f[(size_t)(i0+r)*HD + c];
  }
  float acco[4][4]={};  // [mi(i)][hi(h)]
  for (int jt=0; jt<16; ++jt){
    int j0 = blockIdx.y*1024 + jt*64;
    __syncthreads();
    for (int idx=tid; idx<4096; idx+=256){
      int r=idx>>6, c=idx&63;
      float v = f[(size_t)(j0+r)*HD + c];
      FjT[c][r] = v;
      Fj [r][c] = v;
    }
    __syncthreads();
    float accs[4][4]={};   // [mi(i)][ni(j)]
    for (int k=0;k<64;++k){
      float a[4], b[4];
      #pragma unroll
      for (int i=0;i<4;++i) a[i] = Fi [k][tx*4+i];
      #pragma unroll
      for (int i=0;i<4;++i) b[i] = FjT[k][ty*4+i];
      #pragma unroll
      for (int mi=0;mi<4;++mi)
        #pragma unroll
        for (int ni=0;ni<4;++ni) accs[mi][ni] += a[mi]*b[ni];
    }
    __syncthreads();
    #pragma unroll
    for (int mi=0;mi<4;++mi)
      #pragma unroll
      for (int ni=0;ni<4;++ni)
        FjT[ty*4+ni][tx*4+mi] = __expf(accs[mi][ni]*0.125f);  // P[j][i]
    __syncthreads();
    for (int k=0;k<64;++k){
      float p[4], b[4];
      #pragma unroll
      for (int i=0;i<4;++i) p[i] = FjT[k][tx*4+i];   // P[j=k][i]
      #pragma unroll
      for (int i=0;i<4;++i) b[i] = Fj [k][ty*4+i];   // f[j=k][h]
      #pragma unroll
      for (int mi=0;mi<4;++mi)
        #pragma unroll
        for (int hi=0;hi<4;++hi) acco[mi][hi] += p[mi]*b[hi];
    }
  }
  for (int mi=0;mi<4;++mi)
    for (int hi=0;hi<4;++hi)
      atomicAdd(&dpre[(size_t)(i0+tx*4+mi)*HD + ty*4+hi], acco[mi][hi]);
}

// ---- 7. d = LN2(dpre/rowsum); dmat, sq_d. One wave per row ----
__global__ void k_dln(const float* __restrict__ dpre, const float* __restrict__ rowsum,
                      const float* __restrict__ ln2w, const float* __restrict__ ln2b,
                      const float* __restrict__ wow,
                      float* __restrict__ dmat, float* __restrict__ sq_d){
  int lane = threadIdx.x & 63;
  int n = blockIdx.x*4 + (threadIdx.x>>6);
  float x = dpre[(size_t)n*HD + lane] / rowsum[n];
  float tot = x;
  for (int m=32;m>=1;m>>=1) tot += __shfl_xor(tot,m);
  float mean = tot*(1.f/64.f);
  float dv = x - mean;
  float vv = dv*dv;
  for (int m=32;m>=1;m>>=1) vv += __shfl_xor(vv,m);
  float y = dv*(1.f/sqrtf(vv*(1.f/64.f)+1e-5f))*ln2w[lane] + ln2b[lane];
  dmat[(size_t)n*HD + lane] = y;
  float wv = wow[lane];
  float q = wv*y*y;
  for (int m=32;m>=1;m>>=1) q += __shfl_xor(q,m);
  if (lane==0) sq_d[n] = q;
}

// ---- 8. Hm[n][e] = exp(-(sq_s[e]+sq_d[n]-2*dot(sw[e],d[n])+b)/800), store bf16 ----
__global__ void k_hm(const float* __restrict__ dmat, const float* __restrict__ sw,
                     const float* __restrict__ sq_d, const float* __restrict__ sq_s,
                     const float* __restrict__ wob, bf16* __restrict__ Hm){
  __shared__ float As[64][65]; // [k(h)][m(n)]
  __shared__ float Bs[64][65]; // [k(h)][n(e)]
  int n0 = blockIdx.x*64, e0 = blockIdx.y*64;
  int tid=threadIdx.x, tx=tid&15, ty=tid>>4;
  for (int idx=tid; idx<4096; idx+=256){
    int r=idx>>6, c=idx&63;
    As[c][r] = dmat[(size_t)(n0+r)*HD + c];
    Bs[c][r] = sw  [(size_t)(e0+r)*HD + c];
  }
  __syncthreads();
  float acc[4][4]={};
  for (int k=0;k<64;++k){
    float a[4], b[4];
    #pragma unroll
    for (int i=0;i<4;++i) a[i] = As[k][tx*4+i];
    #pragma unroll
    for (int i=0;i<4;++i) b[i] = Bs[k][ty*4+i];
    #pragma unroll
    for (int mi=0;mi<4;++mi)
      #pragma unroll
      for (int ni=0;ni<4;++ni) acc[mi][ni] += a[mi]*b[ni];
  }
  float bias = wob[0];
  for (int mi=0;mi<4;++mi)
    for (int ni=0;ni<4;++ni){
      int nn = n0+tx*4+mi, ee = e0+ty*4+ni;
      float ta = sq_s[ee] + sq_d[nn] - 2.f*acc[mi][ni] + bias;
      float arg = -ta*(1.f/800.f);
      if (!(arg > -88.f)) arg = -88.f;
      if (arg > 60.f)     arg = 60.f;
      Hm[(size_t)nn*NE + ee] = __float2bfloat16(__expf(arg));
    }
}

// ---- 9. invDV[n] = (row sum of Hm)^-0.5 ----
__global__ void k_dv(const bf16* __restrict__ Hm, float* __restrict__ invDV){
  __shared__ float sm[256];
  int n = blockIdx.x, t = threadIdx.x;
  const bf16* row = Hm + (size_t)n*NE;
  float a = b2f(row[t]) + b2f(row[t+256]) + b2f(row[t+512]) + b2f(row[t+768]);
  sm[t]=a; __syncthreads();
  for (int s=128;s>0;s>>=1){ if(t<s) sm[t]+=sm[t+s]; __syncthreads(); }
  if (t==0){ float v = sm[0]; invDV[n] = (v>0.f) ? 1.f/sqrtf(v) : 0.f; }
}

// ---- 10. DE col sums -> invDE ----
__global__ void k_de(const bf16* __restrict__ Hm, float* __restrict__ DE){
  int e  = blockIdx.x*256 + threadIdx.x;
  int i0 = blockIdx.y*128;
  float acc=0.f;
  for (int i=0;i<128;++i) acc += b2f(Hm[(size_t)(i0+i)*NE + e]);
  atomicAdd(&DE[e], acc);
}
__global__ void k_invde(float* __restrict__ DE){
  int e = blockIdx.x*256 + threadIdx.x;
  float v = DE[e];
  DE[e] = (v>0.f) ? 1.f/v : 0.f;
}

// ---- 11. out = 0.99*G + 0.01*invDV_i*invDV_j*sum_e Hm[i,e]*invDE[e]*Hm[j,e]
//      symmetric: compute upper-tri 64x64 tiles, mirror via LDS ----
__global__ void k_final(const bf16* __restrict__ Hm, const float* __restrict__ invDE,
                        const float* __restrict__ invDV, const float* __restrict__ G,
                        float* __restrict__ out){
  int bi = blockIdx.x, bj = blockIdx.y;
  if (bj < bi) return;
  __shared__ float As[64][65]; // [k(e)][m(i)]
  __shared__ float Bs[64][65]; // [k(e)][n(j)]
  int i0 = bi*64, j0 = bj*64;
  int tid=threadIdx.x, tx=tid&15, ty=tid>>4;
  float acc[4][4]={};
  for (int k0=0;k0<NE;k0+=64){
    for (int idx=tid; idx<4096; idx+=256){
      int r=idx>>6, c=idx&63;
      As[c][r] = b2f(Hm[(size_t)(i0+r)*NE + k0+c])*invDE[k0+c];
      Bs[c][r] = b2f(Hm[(size_t)(j0+r)*NE + k0+c]);
    }
    __syncthreads();
    for (int k=0;k<64;++k){
      float a[4], b[4];
      #pragma unroll
      for (int i=0;i<4;++i) a[i] = As[k][tx*4+i];
      #pragma unroll
      for (int i=0;i<4;++i) b[i] = Bs[k][ty*4+i];
      #pragma unroll
      for (int mi=0;mi<4;++mi)
        #pragma unroll
        for (int ni=0;ni<4;++ni) acc[mi][ni] += a[mi]*b[ni];
    }
    __syncthreads();
  }
  float gnv[4][4];
  for (int mi=0;mi<4;++mi){
    int ii = i0+tx*4+mi;
    float di = invDV[ii];
    for (int ni=0;ni<4;++ni){
      int jj = j0+ty*4+ni;
      float gn = di*invDV[jj]*acc[mi][ni];
      gnv[mi][ni] = gn;
      size_t o = (size_t)ii*NN + jj;
      out[o] = 0.99f*G[o] + 0.01f*gn;
    }
  }
  if (bi==bj) return;  // uniform across block
  __syncthreads();
  for (int mi=0;mi<4;++mi)
    for (int ni=0;ni<4;++ni)
      As[tx*4+mi][ty*4+ni] = gnv[mi][ni];   // As[i_local][j_local]
  __syncthreads();
  for (int idx=tid; idx<4096; idx+=256){
    int r=idx>>6, c=idx&63;  // r=j_local, c=i_local
    size_t o = (size_t)(j0+r)*NN + i0+c;
    out[o] = 0.99f*G[o] + 0.01f*As[c][r];
  }
}

extern "C" void kernel_launch(void* const* d_in, const int* in_sizes, int n_in,
                              void* d_out, int out_size, void* d_ws, size_t ws_size,
                              hipStream_t stream){
  const float* adj  = (const float*)d_in[0];
  const float* G    = (const float*)d_in[1];
  const float* feats= (const float*)d_in[2];
  const float* Wv   = (const float*)d_in[3];
  const float* lin  = (const float*)d_in[4];
  const float* wow  = (const float*)d_in[5];
  const float* wob  = (const float*)d_in[6];
  const float* ln1w = (const float*)d_in[7];
  const float* ln1b = (const float*)d_in[8];
  const float* ln2w = (const float*)d_in[9];
  const float* ln2b = (const float*)d_in[10];
  float* out = (float*)d_out;

  float* w = (float*)d_ws;
  float* colsum = w; w += NE;
  float* DE     = w; w += NE;   // becomes invDE in place
  float* sq_s   = w; w += NE;
  float* rowsum = w; w += NN;
  float* sq_d   = w; w += NN;
  float* invDV  = w; w += NN;
  float* ecT    = w; w += NE*DIN;
  float* swp    = w; w += NE*HD;
  float* f      = w; w += NN*HD;
  float* dpre   = w; w += NN*HD;
  float* dmat   = w; w += NN*HD;
  bf16*  Hm     = (bf16*)w;     // NN*NE bf16 = 8 MB

  hipMemsetAsync(colsum, 0, NE*sizeof(float), stream);
  hipMemsetAsync(DE,     0, NE*sizeof(float), stream);
  hipMemsetAsync(rowsum, 0, NN*sizeof(float), stream);
  hipMemsetAsync(ecT,    0, (size_t)NE*DIN*sizeof(float), stream);
  hipMemsetAsync(f,      0, (size_t)NN*HD*sizeof(float), stream);
  hipMemsetAsync(dpre,   0, (size_t)NN*HD*sizeof(float), stream);

  k_colsum <<<dim3(4,32),    256, 0, stream>>>(adj, colsum);
  k_ect    <<<dim3(4,16,16), 256, 0, stream>>>(feats, adj, ecT);
  k_s      <<<NE,             64, 0, stream>>>(ecT, colsum, lin, ln1w, ln1b, wow, swp, sq_s);
  k_f      <<<dim3(64,4),    256, 0, stream>>>(feats, Wv, f);
  k_rowsum <<<dim3(64,8),    256, 0, stream>>>(f, rowsum);
  k_av     <<<dim3(64,4),    256, 0, stream>>>(f, dpre);
  k_dln    <<<NN/4,          256, 0, stream>>>(dpre, rowsum, ln2w, ln2b, wow, dmat, sq_d);
  k_hm     <<<dim3(64,16),   256, 0, stream>>>(dmat, swp, sq_d, sq_s, wob, Hm);
  k_dv     <<<NN,            256, 0, stream>>>(Hm, invDV);
  k_de     <<<dim3(4,32),    256, 0, stream>>>(Hm, DE);
  k_invde  <<<4,             256, 0, stream>>>(DE);
  k_final  <<<dim3(64,64),   256, 0, stream>>>(Hm, DE, invDV, G, out);
}